// Round 2
// baseline (373.566 us; speedup 1.0000x reference)
//
#include <hip/hip_runtime.h>
#include <hip/hip_bf16.h>

typedef unsigned char uchar_t;
typedef __attribute__((ext_vector_type(4))) float f32x4;

#define B_SZ 8192
#define D_FT 784
#define K_PAD 832   // 13 * 64 fp8 bytes per row
#define N_KT 13
#define THRESH 0.9f

#define GLOBAL_AS(p) ((const __attribute__((address_space(1))) void*)(p))
#define LDS_AS(p)    ((__attribute__((address_space(3))) void*)(p))

// R7: adj is ~all zeros (threshold 0.9 on squared cosines of random-ish rows,
// diagonal excluded). Stream the zeros with a dedicated NT fill kernel at full
// write BW; gram only stores sub-tiles that actually contain a 1 (__any guard).
__global__ __launch_bounds__(256) void zero_adj_kernel(float* __restrict__ adj)
{
    const size_t n4 = (size_t)B_SZ * B_SZ / 4;
    f32x4 z = {0.f, 0.f, 0.f, 0.f};
    f32x4* p = (f32x4*)adj;
    for (size_t i = (size_t)blockIdx.x * 256 + threadIdx.x; i < n4;
         i += (size_t)gridDim.x * 256)
        __builtin_nontemporal_store(z, p + i);
}

// Wave-per-row preproc: 2048 blocks x 4 waves; wave w handles row blockIdx*4+w.
// conv 2x2/s2 + bias -> 4x4 unitary -> qf (LDS, fp32), row norm -> qn fp8 e4m3
// (packed via v_cvt_pk_fp8_f32, padded to 832), logits + log_softmax (fp32).
__global__ __launch_bounds__(256) void preproc_kernel(
    const float* __restrict__ x, const float* __restrict__ conv_w,
    const float* __restrict__ conv_b, const float* __restrict__ unitary,
    const float* __restrict__ lin_w, const float* __restrict__ lin_b,
    float* __restrict__ log_probs, uchar_t* __restrict__ qn)
{
    __shared__ float xr[4][784];
    __shared__ float qf[4][784];

    const int t = threadIdx.x, lane = t & 63, wave = t >> 6;
    const int b = blockIdx.x * 4 + wave;
    float* xw = xr[wave];
    float* qw = qf[wave];

    const float4* xsrc = (const float4*)(x + (size_t)b * 784);
    #pragma unroll
    for (int i = lane; i < 196; i += 64) ((float4*)xw)[i] = xsrc[i];
    __syncthreads();

    float sumsq = 0.f;
    for (int g = lane; g < 196; g += 64) {
        const int c = g / 49, p = g % 49;
        const float w00 = conv_w[c*4+0], w01 = conv_w[c*4+1];
        const float w10 = conv_w[c*4+2], w11 = conv_w[c*4+3];
        const float bcv = conv_b[c];
        float feat[4];
        #pragma unroll
        for (int j = 0; j < 4; ++j) {
            const int s = 4*p + j;
            const int h = s / 14, wq = s % 14;
            const float* px = &xw[(2*h)*28 + 2*wq];
            feat[j] = bcv + w00*px[0] + w01*px[1] + w10*px[28] + w11*px[29];
        }
        #pragma unroll
        for (int w = 0; w < 4; ++w) {
            float v = unitary[w*4+0]*feat[0] + unitary[w*4+1]*feat[1]
                    + unitary[w*4+2]*feat[2] + unitary[w*4+3]*feat[3];
            qw[4*g + w] = v;
            sumsq += v * v;
        }
    }
    __syncthreads();

    #pragma unroll
    for (int off = 1; off < 64; off <<= 1) sumsq += __shfl_xor(sumsq, off, 64);
    const float inv = 1.0f / (sqrtf(sumsq) + 1e-12f);

    // qn write: 208 uints (4 fp8 each) = 832 B, zero-padded past 784
    unsigned int* qrow = (unsigned int*)(qn + (size_t)b * K_PAD);
    for (int i = lane; i < 208; i += 64) {
        unsigned int o = 0u;
        if (i < 196) {
            const float v0 = qw[4*i+0] * inv, v1 = qw[4*i+1] * inv;
            const float v2 = qw[4*i+2] * inv, v3 = qw[4*i+3] * inv;
            int lo = __builtin_amdgcn_cvt_pk_fp8_f32(v0, v1, 0, 0);
            o = (unsigned int)__builtin_amdgcn_cvt_pk_fp8_f32(v2, v3, lo, 1);
        }
        qrow[i] = o;
    }

    float acc[10];
    #pragma unroll
    for (int cl = 0; cl < 10; ++cl) acc[cl] = 0.f;
    for (int k = lane; k < 784; k += 64) {
        const float v = qw[k];
        #pragma unroll
        for (int cl = 0; cl < 10; ++cl) acc[cl] += v * lin_w[cl*784 + k];
    }
    #pragma unroll
    for (int cl = 0; cl < 10; ++cl) {
        #pragma unroll
        for (int off = 1; off < 64; off <<= 1)
            acc[cl] += __shfl_xor(acc[cl], off, 64);
        acc[cl] += lin_b[cl];
    }
    if (lane == 0) {
        float mx = -1e30f;
        #pragma unroll
        for (int cl = 0; cl < 10; ++cl) mx = fmaxf(mx, acc[cl]);
        float se = 0.f;
        #pragma unroll
        for (int cl = 0; cl < 10; ++cl) se += expf(acc[cl] - mx);
        const float lse = mx + logf(se);
        #pragma unroll
        for (int cl = 0; cl < 10; ++cl)
            log_probs[(size_t)b*10 + cl] = acc[cl] - lse;
    }
}

// Symmetric 128x128-tile fp8 Gram GEMM, BK=64 (13 kt), 4 waves (64x64 tiles).
// R7: 2-buffer LDS (32 KB -> 4 blocks/CU, vs R6's 3-buf 48 KB / 3 blocks),
// depth-1 prefetch with ONE s_barrier per kt, sparse epilogue (stores only
// sub-tiles containing a 1 -- zeros come from zero_adj_kernel).
//
// Pipeline safety (1 barrier/kt, 2 buffers):
//   - vmcnt(0) at top of kt: the only outstanding loads are this wave's 4
//     for tile kt (issued post-barrier in kt-1). barrier(kt) then guarantees
//     every wave's tile-kt data is in buffer p = kt&1, AND every wave's
//     ds_reads of tile kt-1 completed (lgkm-waited before its MFMAs, which
//     precede the barrier).
//   - STAGE(kt+1) issued after barrier(kt) overwrites buffer p^1 (tile kt-1),
//     which is dead by the argument above. Its async LDS writes land during
//     our MFMA phase on buffer p -- no reader until after barrier(kt+1).
//
// LDS layout per 16-row block rb (1024 B): [kchunk 0..3][row 0..15][16 B];
// glds lane map row=lane&15, kchunk=lane>>4 matches exactly (linear dest).
// Fragment: ds_read_b64 at chunk 2s+(quad>>1), half quad&1 -> structural-min
// bank load (4/bank). Per kt per wave: 4 glds + 16 ds_read_b64 + 32 mfma.
__global__ __launch_bounds__(256, 4) void gram_kernel(
    const uchar_t* __restrict__ qn, float* __restrict__ adj)
{
    // XCD-bijective swizzle: 2080 = 8 * 260, XCD x gets contiguous ids
    // [x*260, (x+1)*260) -> consecutive ids share br -> A-panel L2 reuse.
    const int t0 = blockIdx.x;
    int tl = (t0 & 7) * 260 + (t0 >> 3);
    // triangular decode: row br owns (64-br) blocks; cum(r) = r*(129-r)/2
    int br = (int)((129.0 - sqrt(16641.0 - 8.0 * (double)tl)) * 0.5);
    while ((br + 1) * (129 - (br + 1)) / 2 <= tl) ++br;
    while (br * (129 - br) / 2 > tl) --br;
    const int bc = br + (tl - br * (129 - br) / 2);

    __shared__ uchar_t ldsA[2][8192] __attribute__((aligned(16)));  // 2x8KB
    __shared__ uchar_t ldsB[2][8192] __attribute__((aligned(16)));  // 2x8KB

    const int t = threadIdx.x;
    const int lane = t & 63, wave = t >> 6;
    const int wr = wave >> 1, wc = wave & 1;
    const int quad = lane >> 4, l16 = lane & 15;

    // staging: wave w stages row-blocks {w, w+4} of A and B (4 glds/kt)
    const int srow = lane & 15, sck = (lane >> 4) * 16;  // byte offset in row
    const uchar_t* gA0 = qn + (size_t)(br*128 + wave*16     + srow) * K_PAD + sck;
    const uchar_t* gA1 = qn + (size_t)(br*128 + (wave+4)*16 + srow) * K_PAD + sck;
    const uchar_t* gB0 = qn + (size_t)(bc*128 + wave*16     + srow) * K_PAD + sck;
    const uchar_t* gB1 = qn + (size_t)(bc*128 + (wave+4)*16 + srow) * K_PAD + sck;
    const int ld0 = wave * 1024, ld1 = (wave + 4) * 1024;

    #define STAGE(p, koff) do {                                                            \
        __builtin_amdgcn_global_load_lds(GLOBAL_AS(gA0 + (koff)), LDS_AS(&ldsA[p][ld0]), 16, 0, 0); \
        __builtin_amdgcn_global_load_lds(GLOBAL_AS(gA1 + (koff)), LDS_AS(&ldsA[p][ld1]), 16, 0, 0); \
        __builtin_amdgcn_global_load_lds(GLOBAL_AS(gB0 + (koff)), LDS_AS(&ldsB[p][ld0]), 16, 0, 0); \
        __builtin_amdgcn_global_load_lds(GLOBAL_AS(gB1 + (koff)), LDS_AS(&ldsB[p][ld1]), 16, 0, 0); \
    } while (0)

    f32x4 acc[4][4] = {};
    STAGE(0, 0);

    #pragma unroll
    for (int kt = 0; kt < N_KT; ++kt) {
        const int p = kt & 1;

        asm volatile("" ::: "memory");
        __builtin_amdgcn_s_waitcnt(0xF70);   // vmcnt(0): tile kt landed (ours)
        __builtin_amdgcn_s_barrier();        // everyone's landed; p^1 is dead
        asm volatile("" ::: "memory");

        if (kt + 1 < N_KT) STAGE(p ^ 1, (kt + 1) * 64);   // prefetch next
        asm volatile("" ::: "memory");

        #pragma unroll
        for (int s = 0; s < 2; ++s) {
            const int fo = (2*s + (quad >> 1))*256 + l16*16 + (quad & 1)*8;
            long bfr[4];
            #pragma unroll
            for (int ni = 0; ni < 4; ++ni)
                bfr[ni] = *(const long*)&ldsB[p][(wc*4 + ni)*1024 + fo];
            #pragma unroll
            for (int mi = 0; mi < 4; ++mi) {
                const long af = *(const long*)&ldsA[p][(wr*4 + mi)*1024 + fo];
                #pragma unroll
                for (int ni = 0; ni < 4; ++ni)
                    acc[mi][ni] = __builtin_amdgcn_mfma_f32_16x16x32_fp8_fp8(
                        af, bfr[ni], acc[mi][ni], 0, 0, 0);
            }
        }
    }
    #undef STAGE

    // Sparse epilogue: fid = c^2, threshold, zero diagonal. Zeros are already
    // in adj (zero_adj_kernel); only store sub-tiles that contain a 1.
    // Wave-uniform __any guard -> in the common case (no edges) zero stores.
    const bool offdiag = (br != bc);
    #pragma unroll
    for (int mi = 0; mi < 4; ++mi) {
        const int gr0 = br*128 + wr*64 + mi*16 + quad*4;
        #pragma unroll
        for (int ni = 0; ni < 4; ++ni) {
            const int gc = bc*128 + wc*64 + ni*16 + l16;
            const f32x4 v = acc[mi][ni];
            float o[4];
            bool h = false;
            #pragma unroll
            for (int r = 0; r < 4; ++r) {
                o[r] = (v[r]*v[r] >= THRESH && (gr0 + r) != gc) ? 1.0f : 0.0f;
                h = h || (o[r] != 0.0f);
            }
            if (__any(h)) {
                #pragma unroll
                for (int r = 0; r < 4; ++r)
                    adj[(size_t)(gr0 + r) * B_SZ + gc] = o[r];
                if (offdiag)
                    *(float4*)&adj[(size_t)gc * B_SZ + gr0] =
                        make_float4(o[0], o[1], o[2], o[3]);
            }
        }
    }
}

extern "C" void kernel_launch(void* const* d_in, const int* in_sizes, int n_in,
                              void* d_out, int out_size, void* d_ws, size_t ws_size,
                              hipStream_t stream) {
    const float* x       = (const float*)d_in[0];
    const float* conv_w  = (const float*)d_in[1];
    const float* conv_b  = (const float*)d_in[2];
    const float* unitary = (const float*)d_in[3];
    const float* lin_w   = (const float*)d_in[4];
    const float* lin_b   = (const float*)d_in[5];

    float* log_probs = (float*)d_out;
    float* adj       = (float*)d_out + (size_t)B_SZ * 10;
    uchar_t* qn      = (uchar_t*)d_ws;   // [8192, 832] fp8 e4m3

    // Order: zero-fill first (268 MB stream), then preproc (qn lands L2-warm
    // right before gram reads it), then gram.
    zero_adj_kernel<<<4096, 256, 0, stream>>>(adj);
    preproc_kernel<<<B_SZ / 4, 256, 0, stream>>>(x, conv_w, conv_b, unitary,
                                                 lin_w, lin_b, log_probs, qn);
    gram_kernel<<<2080, 256, 0, stream>>>(qn, adj);
}

// Round 3
// 342.838 us; speedup vs baseline: 1.0896x; 1.0896x over previous
//
#include <hip/hip_runtime.h>
#include <hip/hip_bf16.h>

typedef unsigned char uchar_t;
typedef __attribute__((ext_vector_type(4))) float f32x4;

#define B_SZ 8192
#define D_FT 784
#define K_PAD 832   // 13 * 64 fp8 bytes per row
#define N_KT 13
#define THRESH 0.9f

#define GLOBAL_AS(p) ((const __attribute__((address_space(1))) void*)(p))
#define LDS_AS(p)    ((__attribute__((address_space(3))) void*)(p))

// Wave-per-row preproc: 2048 blocks x 4 waves; wave w handles row blockIdx*4+w.
// conv 2x2/s2 + bias -> 4x4 unitary -> qf (LDS, fp32), row norm -> qn fp8 e4m3
// (packed via v_cvt_pk_fp8_f32, padded to 832), logits + log_softmax (fp32).
__global__ __launch_bounds__(256) void preproc_kernel(
    const float* __restrict__ x, const float* __restrict__ conv_w,
    const float* __restrict__ conv_b, const float* __restrict__ unitary,
    const float* __restrict__ lin_w, const float* __restrict__ lin_b,
    float* __restrict__ log_probs, uchar_t* __restrict__ qn)
{
    __shared__ float xr[4][784];
    __shared__ float qf[4][784];

    const int t = threadIdx.x, lane = t & 63, wave = t >> 6;
    const int b = blockIdx.x * 4 + wave;
    float* xw = xr[wave];
    float* qw = qf[wave];

    const float4* xsrc = (const float4*)(x + (size_t)b * 784);
    #pragma unroll
    for (int i = lane; i < 196; i += 64) ((float4*)xw)[i] = xsrc[i];
    __syncthreads();

    float sumsq = 0.f;
    for (int g = lane; g < 196; g += 64) {
        const int c = g / 49, p = g % 49;
        const float w00 = conv_w[c*4+0], w01 = conv_w[c*4+1];
        const float w10 = conv_w[c*4+2], w11 = conv_w[c*4+3];
        const float bcv = conv_b[c];
        float feat[4];
        #pragma unroll
        for (int j = 0; j < 4; ++j) {
            const int s = 4*p + j;
            const int h = s / 14, wq = s % 14;
            const float* px = &xw[(2*h)*28 + 2*wq];
            feat[j] = bcv + w00*px[0] + w01*px[1] + w10*px[28] + w11*px[29];
        }
        #pragma unroll
        for (int w = 0; w < 4; ++w) {
            float v = unitary[w*4+0]*feat[0] + unitary[w*4+1]*feat[1]
                    + unitary[w*4+2]*feat[2] + unitary[w*4+3]*feat[3];
            qw[4*g + w] = v;
            sumsq += v * v;
        }
    }
    __syncthreads();

    #pragma unroll
    for (int off = 1; off < 64; off <<= 1) sumsq += __shfl_xor(sumsq, off, 64);
    const float inv = 1.0f / (sqrtf(sumsq) + 1e-12f);

    // qn write: 208 uints (4 fp8 each) = 832 B, zero-padded past 784
    unsigned int* qrow = (unsigned int*)(qn + (size_t)b * K_PAD);
    for (int i = lane; i < 208; i += 64) {
        unsigned int o = 0u;
        if (i < 196) {
            const float v0 = qw[4*i+0] * inv, v1 = qw[4*i+1] * inv;
            const float v2 = qw[4*i+2] * inv, v3 = qw[4*i+3] * inv;
            int lo = __builtin_amdgcn_cvt_pk_fp8_f32(v0, v1, 0, 0);
            o = (unsigned int)__builtin_amdgcn_cvt_pk_fp8_f32(v2, v3, lo, 1);
        }
        qrow[i] = o;
    }

    float acc[10];
    #pragma unroll
    for (int cl = 0; cl < 10; ++cl) acc[cl] = 0.f;
    for (int k = lane; k < 784; k += 64) {
        const float v = qw[k];
        #pragma unroll
        for (int cl = 0; cl < 10; ++cl) acc[cl] += v * lin_w[cl*784 + k];
    }
    #pragma unroll
    for (int cl = 0; cl < 10; ++cl) {
        #pragma unroll
        for (int off = 1; off < 64; off <<= 1)
            acc[cl] += __shfl_xor(acc[cl], off, 64);
        acc[cl] += lin_b[cl];
    }
    if (lane == 0) {
        float mx = -1e30f;
        #pragma unroll
        for (int cl = 0; cl < 10; ++cl) mx = fmaxf(mx, acc[cl]);
        float se = 0.f;
        #pragma unroll
        for (int cl = 0; cl < 10; ++cl) se += expf(acc[cl] - mx);
        const float lse = mx + logf(se);
        #pragma unroll
        for (int cl = 0; cl < 10; ++cl)
            log_probs[(size_t)b*10 + cl] = acc[cl] - lse;
    }
}

// Symmetric 128x128-tile fp8 Gram GEMM, BK=64 (13 kt), 4 waves (64x64 tiles).
// R8: zero-fill of this block's adj tile(s) is INJECTED into the K-loop
// (3 coalesced NT float4 zero-stores per thread per kt) so the 268 MB zero
// stream drains during the loop's load-latency stall slack instead of
// costing a serial 43 us standalone kernel (R2's zero_adj, deleted).
//
// vmcnt discipline with store injection (stores count in vmcnt on gfx9):
//   per-kt issue order: [STAGE kt+1: 4 glds][3 zero stores]  (order pinned
//   by memory-clobber asm). At top of kt: outstanding (oldest->youngest) =
//   [lingering old stores][4 glds for tile kt][3 stores]. Waiting vmcnt(3)
//   retires everything but the 3 youngest -> tile-kt glds are in LDS, and
//   the zero-store stream is never force-drained inside the loop.
//   kt=0 uses vmcnt(0) (only the prologue's 4 glds are outstanding).
//   Store count is EXACTLY 3/thread/kt (index masked by pow2 tile size;
//   duplicate re-zeroes are harmless) so the count is wave-invariant.
//
// Epilogue ordering: vmcnt(0) + s_barrier makes every wave's zero stores
// visible before the sparse 1-fixup stores (same addresses, any thread).
//
// Pipeline (unchanged from R7): 2-buffer LDS, ONE s_barrier per kt.
// LDS layout per 16-row block rb (1024 B): [kchunk 0..3][row 0..15][16 B];
// glds lane map row=lane&15, kchunk=lane>>4 matches exactly (linear dest).
// Fragment: ds_read_b64 at chunk 2s+(quad>>1), half quad&1 -> structural-min
// bank load (4/bank). Per kt per wave: 4 glds + 16 ds_read_b64 + 32 mfma.
__global__ __launch_bounds__(256, 4) void gram_kernel(
    const uchar_t* __restrict__ qn, float* __restrict__ adj)
{
    // XCD-bijective swizzle: 2080 = 8 * 260, XCD x gets contiguous ids
    // [x*260, (x+1)*260) -> consecutive ids share br -> A-panel L2 reuse.
    const int t0 = blockIdx.x;
    int tl = (t0 & 7) * 260 + (t0 >> 3);
    // triangular decode: row br owns (64-br) blocks; cum(r) = r*(129-r)/2
    int br = (int)((129.0 - sqrt(16641.0 - 8.0 * (double)tl)) * 0.5);
    while ((br + 1) * (129 - (br + 1)) / 2 <= tl) ++br;
    while (br * (129 - br) / 2 > tl) --br;
    const int bc = br + (tl - br * (129 - br) / 2);

    __shared__ uchar_t ldsA[2][8192] __attribute__((aligned(16)));  // 2x8KB
    __shared__ uchar_t ldsB[2][8192] __attribute__((aligned(16)));  // 2x8KB

    const int t = threadIdx.x;
    const int lane = t & 63, wave = t >> 6;
    const int wr = wave >> 1, wc = wave & 1;
    const int quad = lane >> 4, l16 = lane & 15;

    const bool offdiag = (br != bc);
    const int br128 = br * 128, bc128 = bc * 128;
    // zero-injection geometry: off-diag blocks own 2 mirror tiles (8192
    // float4s), diag blocks 1 tile (4096). Pow2 mask -> exactly 3 stores
    // per thread per kt, excess indices wrap (harmless duplicate zero).
    const int zmask = offdiag ? 8191 : 4095;

    // staging: wave w stages row-blocks {w, w+4} of A and B (4 glds/kt)
    const int srow = lane & 15, sck = (lane >> 4) * 16;  // byte offset in row
    const uchar_t* gA0 = qn + (size_t)(br*128 + wave*16     + srow) * K_PAD + sck;
    const uchar_t* gA1 = qn + (size_t)(br*128 + (wave+4)*16 + srow) * K_PAD + sck;
    const uchar_t* gB0 = qn + (size_t)(bc*128 + wave*16     + srow) * K_PAD + sck;
    const uchar_t* gB1 = qn + (size_t)(bc*128 + (wave+4)*16 + srow) * K_PAD + sck;
    const int ld0 = wave * 1024, ld1 = (wave + 4) * 1024;

    #define STAGE(p, koff) do {                                                            \
        __builtin_amdgcn_global_load_lds(GLOBAL_AS(gA0 + (koff)), LDS_AS(&ldsA[p][ld0]), 16, 0, 0); \
        __builtin_amdgcn_global_load_lds(GLOBAL_AS(gA1 + (koff)), LDS_AS(&ldsA[p][ld1]), 16, 0, 0); \
        __builtin_amdgcn_global_load_lds(GLOBAL_AS(gB0 + (koff)), LDS_AS(&ldsB[p][ld0]), 16, 0, 0); \
        __builtin_amdgcn_global_load_lds(GLOBAL_AS(gB1 + (koff)), LDS_AS(&ldsB[p][ld1]), 16, 0, 0); \
    } while (0)

    f32x4 acc[4][4] = {};
    STAGE(0, 0);

    #pragma unroll
    for (int kt = 0; kt < N_KT; ++kt) {
        const int p = kt & 1;

        asm volatile("" ::: "memory");
        if (kt == 0)
            __builtin_amdgcn_s_waitcnt(0xF70);   // vmcnt(0): prologue glds
        else
            __builtin_amdgcn_s_waitcnt(0xF73);   // vmcnt(3): glds done, 3
                                                 // youngest (zero stores)
                                                 // may remain in flight
        __builtin_amdgcn_s_barrier();            // tile kt in LDS; p^1 dead
        asm volatile("" ::: "memory");

        if (kt + 1 < N_KT) STAGE(p ^ 1, (kt + 1) * 64);   // prefetch next
        asm volatile("" ::: "memory");

        // zero-injection: exactly 3 coalesced NT float4 stores per thread.
        // Issued AFTER the glds (vmcnt counting relies on this order).
        {
            f32x4 z = {0.f, 0.f, 0.f, 0.f};
            #pragma unroll
            for (int j = 0; j < 3; ++j) {
                const int idx  = (kt * 768 + j * 256 + t) & zmask;
                const int tile = idx >> 12;            // always 0 for diag
                const int r    = (idx >> 5) & 127;
                const int c4   = idx & 31;
                const int rowb = tile ? bc128 : br128;
                const int colb = tile ? br128 : bc128;
                __builtin_nontemporal_store(
                    z, (f32x4*)adj + (size_t)(rowb + r) * 2048 + (colb >> 2) + c4);
            }
        }
        asm volatile("" ::: "memory");

        #pragma unroll
        for (int s = 0; s < 2; ++s) {
            const int fo = (2*s + (quad >> 1))*256 + l16*16 + (quad & 1)*8;
            long bfr[4];
            #pragma unroll
            for (int ni = 0; ni < 4; ++ni)
                bfr[ni] = *(const long*)&ldsB[p][(wc*4 + ni)*1024 + fo];
            #pragma unroll
            for (int mi = 0; mi < 4; ++mi) {
                const long af = *(const long*)&ldsA[p][(wr*4 + mi)*1024 + fo];
                #pragma unroll
                for (int ni = 0; ni < 4; ++ni)
                    acc[mi][ni] = __builtin_amdgcn_mfma_f32_16x16x32_fp8_fp8(
                        af, bfr[ni], acc[mi][ni], 0, 0, 0);
            }
        }
    }
    #undef STAGE

    // Order all zero stores (block-wide) before the sparse 1-fixups.
    asm volatile("" ::: "memory");
    __builtin_amdgcn_s_waitcnt(0xF70);   // vmcnt(0): this wave's zeros done
    __builtin_amdgcn_s_barrier();        // all waves' zeros done
    asm volatile("" ::: "memory");

    // Sparse epilogue: fid = c^2, threshold, zero diagonal. Zeros already
    // written above; only store sub-tiles that contain a 1 (__any guard).
    #pragma unroll
    for (int mi = 0; mi < 4; ++mi) {
        const int gr0 = br128 + wr*64 + mi*16 + quad*4;
        #pragma unroll
        for (int ni = 0; ni < 4; ++ni) {
            const int gc = bc128 + wc*64 + ni*16 + l16;
            const f32x4 v = acc[mi][ni];
            float o[4];
            bool h = false;
            #pragma unroll
            for (int r = 0; r < 4; ++r) {
                o[r] = (v[r]*v[r] >= THRESH && (gr0 + r) != gc) ? 1.0f : 0.0f;
                h = h || (o[r] != 0.0f);
            }
            if (__any(h)) {
                #pragma unroll
                for (int r = 0; r < 4; ++r)
                    adj[(size_t)(gr0 + r) * B_SZ + gc] = o[r];
                if (offdiag)
                    *(float4*)&adj[(size_t)gc * B_SZ + gr0] =
                        make_float4(o[0], o[1], o[2], o[3]);
            }
        }
    }
}

extern "C" void kernel_launch(void* const* d_in, const int* in_sizes, int n_in,
                              void* d_out, int out_size, void* d_ws, size_t ws_size,
                              hipStream_t stream) {
    const float* x       = (const float*)d_in[0];
    const float* conv_w  = (const float*)d_in[1];
    const float* conv_b  = (const float*)d_in[2];
    const float* unitary = (const float*)d_in[3];
    const float* lin_w   = (const float*)d_in[4];
    const float* lin_b   = (const float*)d_in[5];

    float* log_probs = (float*)d_out;
    float* adj       = (float*)d_out + (size_t)B_SZ * 10;
    uchar_t* qn      = (uchar_t*)d_ws;   // [8192, 832] fp8 e4m3

    preproc_kernel<<<B_SZ / 4, 256, 0, stream>>>(x, conv_w, conv_b, unitary,
                                                 lin_w, lin_b, log_probs, qn);
    gram_kernel<<<2080, 256, 0, stream>>>(qn, adj);
}

// Round 4
// 340.375 us; speedup vs baseline: 1.0975x; 1.0072x over previous
//
#include <hip/hip_runtime.h>
#include <hip/hip_bf16.h>

typedef unsigned char uchar_t;
typedef __attribute__((ext_vector_type(4))) float f32x4;

#define B_SZ 8192
#define D_FT 784
#define N_KT 13
#define PLANE_U32 131072   // 8192 rows * 16 uints (64 B) per plane
#define PLANE_B   524288   // plane stride in bytes
#define THRESH 0.9f

#define GLOBAL_AS(p) ((const __attribute__((address_space(1))) void*)(p))
#define LDS_AS(p)    ((__attribute__((address_space(3))) void*)(p))

// Wave-per-row preproc: 2048 blocks x 4 waves; wave w handles row blockIdx*4+w.
// conv 2x2/s2 + bias -> 4x4 unitary -> qf (LDS, fp32), row norm -> qn fp8 e4m3.
// R9: qn is written K-PLANE-BLOCKED: qn[kt][row][64 B] (13 planes of 512 KB)
// so gram's per-kt staging reads are fully contiguous (see gram comment).
__global__ __launch_bounds__(256) void preproc_kernel(
    const float* __restrict__ x, const float* __restrict__ conv_w,
    const float* __restrict__ conv_b, const float* __restrict__ unitary,
    const float* __restrict__ lin_w, const float* __restrict__ lin_b,
    float* __restrict__ log_probs, uchar_t* __restrict__ qn)
{
    __shared__ float xr[4][784];
    __shared__ float qf[4][784];

    const int t = threadIdx.x, lane = t & 63, wave = t >> 6;
    const int b = blockIdx.x * 4 + wave;
    float* xw = xr[wave];
    float* qw = qf[wave];

    const float4* xsrc = (const float4*)(x + (size_t)b * 784);
    #pragma unroll
    for (int i = lane; i < 196; i += 64) ((float4*)xw)[i] = xsrc[i];
    __syncthreads();

    float sumsq = 0.f;
    for (int g = lane; g < 196; g += 64) {
        const int c = g / 49, p = g % 49;
        const float w00 = conv_w[c*4+0], w01 = conv_w[c*4+1];
        const float w10 = conv_w[c*4+2], w11 = conv_w[c*4+3];
        const float bcv = conv_b[c];
        float feat[4];
        #pragma unroll
        for (int j = 0; j < 4; ++j) {
            const int s = 4*p + j;
            const int h = s / 14, wq = s % 14;
            const float* px = &xw[(2*h)*28 + 2*wq];
            feat[j] = bcv + w00*px[0] + w01*px[1] + w10*px[28] + w11*px[29];
        }
        #pragma unroll
        for (int w = 0; w < 4; ++w) {
            float v = unitary[w*4+0]*feat[0] + unitary[w*4+1]*feat[1]
                    + unitary[w*4+2]*feat[2] + unitary[w*4+3]*feat[3];
            qw[4*g + w] = v;
            sumsq += v * v;
        }
    }
    __syncthreads();

    #pragma unroll
    for (int off = 1; off < 64; off <<= 1) sumsq += __shfl_xor(sumsq, off, 64);
    const float inv = 1.0f / (sqrtf(sumsq) + 1e-12f);

    // qn write, plane-blocked: uint i of this row -> plane i>>4, word i&15.
    // 208 uints = 13 planes x 16 uints (64 B); zero-padded past 784 fp8.
    // Lanes i..i+15 share a plane -> 64 B contiguous per 16-lane segment.
    unsigned int* qbase = (unsigned int*)qn;
    for (int i = lane; i < 208; i += 64) {
        unsigned int o = 0u;
        if (i < 196) {
            const float v0 = qw[4*i+0] * inv, v1 = qw[4*i+1] * inv;
            const float v2 = qw[4*i+2] * inv, v3 = qw[4*i+3] * inv;
            int lo = __builtin_amdgcn_cvt_pk_fp8_f32(v0, v1, 0, 0);
            o = (unsigned int)__builtin_amdgcn_cvt_pk_fp8_f32(v2, v3, lo, 1);
        }
        qbase[(size_t)(i >> 4) * PLANE_U32 + (size_t)b * 16 + (i & 15)] = o;
    }

    float acc[10];
    #pragma unroll
    for (int cl = 0; cl < 10; ++cl) acc[cl] = 0.f;
    for (int k = lane; k < 784; k += 64) {
        const float v = qw[k];
        #pragma unroll
        for (int cl = 0; cl < 10; ++cl) acc[cl] += v * lin_w[cl*784 + k];
    }
    #pragma unroll
    for (int cl = 0; cl < 10; ++cl) {
        #pragma unroll
        for (int off = 1; off < 64; off <<= 1)
            acc[cl] += __shfl_xor(acc[cl], off, 64);
        acc[cl] += lin_b[cl];
    }
    if (lane == 0) {
        float mx = -1e30f;
        #pragma unroll
        for (int cl = 0; cl < 10; ++cl) mx = fmaxf(mx, acc[cl]);
        float se = 0.f;
        #pragma unroll
        for (int cl = 0; cl < 10; ++cl) se += expf(acc[cl] - mx);
        const float lse = mx + logf(se);
        #pragma unroll
        for (int cl = 0; cl < 10; ++cl)
            log_probs[(size_t)b*10 + cl] = acc[cl] - lse;
    }
}

// Symmetric 128x128-tile fp8 Gram GEMM, BK=64 (13 kt), 4 waves (64x64 tiles).
// R9: qn is K-plane-blocked [kt][row][64B]. One glds now reads 16 rows x 64 B
// CONTIGUOUS (1 KB = 8 fully-used 128 B lines) instead of 16 half-used lines
// at 832-B stride (R3: 2x line over-fetch, ~1024 scattered line reqs/CU/kt
// -> L3-line-BW bound, 18% MfmaUtil). Per kt the whole grid touches ONE
// 512 KB plane -> L2-resident staging on every XCD.
//
// vmcnt discipline with store injection (stores count in vmcnt on gfx9):
//   per-kt issue order: [STAGE kt+1: 4 glds][3 zero stores]. At top of kt:
//   outstanding (oldest->youngest) = [3 stores kt-1][4 glds kt][3 stores kt].
//   Waiting vmcnt(3) retires all but the 3 youngest -> glds are in LDS, the
//   zero-store stream is never force-drained inside the loop. kt=0: vmcnt(0).
//
// Pipeline: 2-buffer LDS, ONE s_barrier per kt (safety argument in R7/R8).
// LDS layout per 16-row block rb (1024 B): [kchunk 0..3][row 0..15][16 B];
// glds lane map row=lane&15, kchunk=lane>>4 -> LDS dest base+lane*16 matches
// global addr (row*64 + kchunk*16) exactly (both linear). Fragment:
// ds_read_b64 at chunk 2s+(quad>>1), half quad&1 -> structural-min bank load.
// Per kt per wave: 4 glds + 16 ds_read_b64 + 32 mfma_16x16x32_fp8_fp8.
__global__ __launch_bounds__(256, 4) void gram_kernel(
    const uchar_t* __restrict__ qn, float* __restrict__ adj)
{
    // XCD-bijective swizzle: 2080 = 8 * 260, XCD x gets contiguous ids
    // [x*260, (x+1)*260) -> consecutive ids share br -> A-panel L2 reuse.
    const int t0 = blockIdx.x;
    int tl = (t0 & 7) * 260 + (t0 >> 3);
    // triangular decode: row br owns (64-br) blocks; cum(r) = r*(129-r)/2
    int br = (int)((129.0 - sqrt(16641.0 - 8.0 * (double)tl)) * 0.5);
    while ((br + 1) * (129 - (br + 1)) / 2 <= tl) ++br;
    while (br * (129 - br) / 2 > tl) --br;
    const int bc = br + (tl - br * (129 - br) / 2);

    __shared__ uchar_t ldsA[2][8192] __attribute__((aligned(16)));  // 2x8KB
    __shared__ uchar_t ldsB[2][8192] __attribute__((aligned(16)));  // 2x8KB

    const int t = threadIdx.x;
    const int lane = t & 63, wave = t >> 6;
    const int wr = wave >> 1, wc = wave & 1;
    const int quad = lane >> 4, l16 = lane & 15;

    const bool offdiag = (br != bc);
    const int br128 = br * 128, bc128 = bc * 128;
    // zero-injection geometry: off-diag blocks own 2 mirror tiles (8192
    // float4s), diag blocks 1 tile (4096). Pow2 mask -> exactly 3 stores
    // per thread per kt, excess indices wrap (harmless duplicate zero).
    const int zmask = offdiag ? 8191 : 4095;

    // staging (plane-blocked): wave w stages row-blocks {w, w+4} of A and B.
    // Per glds: rows rowbase..rowbase+15 x 64 B contiguous; lane -> byte
    // (lane&15)*64 + (lane>>4)*16 == lane*16? No: row-major within the 1 KB
    // region is row*64 + chunk*16; LDS dest is base + lane*16 with
    // row=lane&15, chunk=lane>>4 -> LDS [chunk][row][16] layout as before.
    const int srow = lane & 15, sck = (lane >> 4) * 16;
    const uchar_t* gA0 = qn + (size_t)(br128 + wave*16     + srow) * 64 + sck;
    const uchar_t* gA1 = qn + (size_t)(br128 + (wave+4)*16 + srow) * 64 + sck;
    const uchar_t* gB0 = qn + (size_t)(bc128 + wave*16     + srow) * 64 + sck;
    const uchar_t* gB1 = qn + (size_t)(bc128 + (wave+4)*16 + srow) * 64 + sck;
    const int ld0 = wave * 1024, ld1 = (wave + 4) * 1024;

    #define STAGE(p, koff) do {                                                            \
        __builtin_amdgcn_global_load_lds(GLOBAL_AS(gA0 + (koff)), LDS_AS(&ldsA[p][ld0]), 16, 0, 0); \
        __builtin_amdgcn_global_load_lds(GLOBAL_AS(gA1 + (koff)), LDS_AS(&ldsA[p][ld1]), 16, 0, 0); \
        __builtin_amdgcn_global_load_lds(GLOBAL_AS(gB0 + (koff)), LDS_AS(&ldsB[p][ld0]), 16, 0, 0); \
        __builtin_amdgcn_global_load_lds(GLOBAL_AS(gB1 + (koff)), LDS_AS(&ldsB[p][ld1]), 16, 0, 0); \
    } while (0)

    f32x4 acc[4][4] = {};
    STAGE(0, 0);

    #pragma unroll
    for (int kt = 0; kt < N_KT; ++kt) {
        const int p = kt & 1;

        asm volatile("" ::: "memory");
        if (kt == 0)
            __builtin_amdgcn_s_waitcnt(0xF70);   // vmcnt(0): prologue glds
        else
            __builtin_amdgcn_s_waitcnt(0xF73);   // vmcnt(3): glds done, 3
                                                 // youngest (zero stores)
                                                 // may remain in flight
        __builtin_amdgcn_s_barrier();            // tile kt in LDS; p^1 dead
        asm volatile("" ::: "memory");

        if (kt + 1 < N_KT) STAGE(p ^ 1, (size_t)(kt + 1) * PLANE_B);
        asm volatile("" ::: "memory");

        // zero-injection: exactly 3 coalesced NT float4 stores per thread.
        // Issued AFTER the glds (vmcnt counting relies on this order).
        {
            f32x4 z = {0.f, 0.f, 0.f, 0.f};
            #pragma unroll
            for (int j = 0; j < 3; ++j) {
                const int idx  = (kt * 768 + j * 256 + t) & zmask;
                const int tile = idx >> 12;            // always 0 for diag
                const int r    = (idx >> 5) & 127;
                const int c4   = idx & 31;
                const int rowb = tile ? bc128 : br128;
                const int colb = tile ? br128 : bc128;
                __builtin_nontemporal_store(
                    z, (f32x4*)adj + (size_t)(rowb + r) * 2048 + (colb >> 2) + c4);
            }
        }
        asm volatile("" ::: "memory");

        #pragma unroll
        for (int s = 0; s < 2; ++s) {
            const int fo = (2*s + (quad >> 1))*256 + l16*16 + (quad & 1)*8;
            long bfr[4];
            #pragma unroll
            for (int ni = 0; ni < 4; ++ni)
                bfr[ni] = *(const long*)&ldsB[p][(wc*4 + ni)*1024 + fo];
            #pragma unroll
            for (int mi = 0; mi < 4; ++mi) {
                const long af = *(const long*)&ldsA[p][(wr*4 + mi)*1024 + fo];
                #pragma unroll
                for (int ni = 0; ni < 4; ++ni)
                    acc[mi][ni] = __builtin_amdgcn_mfma_f32_16x16x32_fp8_fp8(
                        af, bfr[ni], acc[mi][ni], 0, 0, 0);
            }
        }
    }
    #undef STAGE

    // Order all zero stores (block-wide) before the sparse 1-fixups.
    asm volatile("" ::: "memory");
    __builtin_amdgcn_s_waitcnt(0xF70);   // vmcnt(0): this wave's zeros done
    __builtin_amdgcn_s_barrier();        // all waves' zeros done
    asm volatile("" ::: "memory");

    // Sparse epilogue: fid = c^2, threshold, zero diagonal. Zeros already
    // written above; only store sub-tiles that contain a 1 (__any guard).
    #pragma unroll
    for (int mi = 0; mi < 4; ++mi) {
        const int gr0 = br128 + wr*64 + mi*16 + quad*4;
        #pragma unroll
        for (int ni = 0; ni < 4; ++ni) {
            const int gc = bc128 + wc*64 + ni*16 + l16;
            const f32x4 v = acc[mi][ni];
            float o[4];
            bool h = false;
            #pragma unroll
            for (int r = 0; r < 4; ++r) {
                o[r] = (v[r]*v[r] >= THRESH && (gr0 + r) != gc) ? 1.0f : 0.0f;
                h = h || (o[r] != 0.0f);
            }
            if (__any(h)) {
                #pragma unroll
                for (int r = 0; r < 4; ++r)
                    adj[(size_t)(gr0 + r) * B_SZ + gc] = o[r];
                if (offdiag)
                    *(float4*)&adj[(size_t)gc * B_SZ + gr0] =
                        make_float4(o[0], o[1], o[2], o[3]);
            }
        }
    }
}

extern "C" void kernel_launch(void* const* d_in, const int* in_sizes, int n_in,
                              void* d_out, int out_size, void* d_ws, size_t ws_size,
                              hipStream_t stream) {
    const float* x       = (const float*)d_in[0];
    const float* conv_w  = (const float*)d_in[1];
    const float* conv_b  = (const float*)d_in[2];
    const float* unitary = (const float*)d_in[3];
    const float* lin_w   = (const float*)d_in[4];
    const float* lin_b   = (const float*)d_in[5];

    float* log_probs = (float*)d_out;
    float* adj       = (float*)d_out + (size_t)B_SZ * 10;
    uchar_t* qn      = (uchar_t*)d_ws;   // 13 planes x [8192][64 B] fp8 e4m3

    preproc_kernel<<<B_SZ / 4, 256, 0, stream>>>(x, conv_w, conv_b, unitary,
                                                 lin_w, lin_b, log_probs, qn);
    gram_kernel<<<2080, 256, 0, stream>>>(qn, adj);
}